// Round 11
// baseline (1882.129 us; speedup 1.0000x reference)
//
#include <hip/hip_runtime.h>
#include <hip/hip_bf16.h>

#define B_ 4
#define C_ 128
#define N_ 4096
#define M_ 4096
#define XSS 68   // row stride (words) for 128x64 fp32 LDS tiles (float4-aligned, bank-staggered)
#define PSS 68

// Zero-workspace fused kernel. Inputs: fp32, dict order. OUTPUT: FLOAT32
// (round-10 diagnostic: a bf16 write into out[0] was invisible to the checker
// => fp32 decode; all R3-R9 ~7.0 failures were bf16-stores-into-fp32-buffer
// decimation artifacts, not binding/layout bugs).
// out[b,n,c] = vout[b,n,c] + x1[b,c,n]  (literal JAX reference mapping).
// Block = 256 threads owns 64 queries. Per 64-key chunk: recompute k,v from
// x2/p2 (linearity: k = Wk*x2 + (Wk*Wpos)*p2), S = q.k/sqrt(C), p = exp(S),
// accumulate PV + denominators. Pure fp32 throughout.
__global__ __launch_bounds__(256) void fused_kernel(
    const float* __restrict__ x1, const float* __restrict__ p1,
    const float* __restrict__ x2, const float* __restrict__ p2,
    const float* __restrict__ Wq, const float* __restrict__ Wk,
    const float* __restrict__ Wv, const float* __restrict__ Wpos,
    float* __restrict__ out) {

    __shared__ float xs[128 * XSS];   // raw x cols [c][pt]
    __shared__ float qs[128 * XSS];   // q [d][i]
    __shared__ float kv[128 * XSS];   // k then v [d][mm] (reused within chunk)
    __shared__ float ps[64 * PSS];    // p [i][mm]
    __shared__ float wqp[128 * 4];    // Wq @ Wpos
    __shared__ float wkp[128 * 4];    // Wk @ Wpos
    __shared__ float pp[3 * 64];      // p1/p2 chunk [k][pt]
    __shared__ float dsums[64];

    const int t = threadIdx.x;
    const int b = blockIdx.y;
    const int n0 = blockIdx.x * 64;
    const float KS2 = 0.12752107168406815f;  // log2(e)/sqrt(128)

    // ---- phase 0: fold Wpos into projections (128x3 each) ----
    for (int idx = t; idx < 768; idx += 256) {
        int which = idx / 384;
        int rem = idx - which * 384;
        int d = rem / 3;
        int k3 = rem - d * 3;
        const float* W = which ? Wk : Wq;
        float s = 0.f;
        #pragma unroll 8
        for (int c = 0; c < 128; ++c)
            s += W[d * 128 + c] * Wpos[c * 3 + k3];
        (which ? wkp : wqp)[d * 4 + k3] = s;
    }

    // ---- phase 0b: load raw x1 tile + p1 chunk ----
    #pragma unroll
    for (int u = 0; u < 32; ++u) {
        int idx = u * 256 + t;
        int i = idx & 63, c = idx >> 6;
        xs[c * XSS + i] = x1[((size_t)b * C_ + c) * N_ + n0 + i];
    }
    if (t < 192) {
        int k3 = t >> 6, i = t & 63;
        pp[k3 * 64 + i] = p1[((size_t)b * 3 + k3) * N_ + n0 + i];
    }
    __syncthreads();

    // ---- phase 0c: q[d][i] = Wq.x1 + wqp.p1 ----
    {
        const int d0 = (t >> 3) * 4;
        const int i0 = (t & 7) * 8;
        float acc[4][8];
        #pragma unroll
        for (int j = 0; j < 4; ++j)
            #pragma unroll
            for (int ii = 0; ii < 8; ++ii)
                acc[j][ii] = wqp[(d0 + j) * 4 + 0] * pp[i0 + ii]
                           + wqp[(d0 + j) * 4 + 1] * pp[64 + i0 + ii]
                           + wqp[(d0 + j) * 4 + 2] * pp[128 + i0 + ii];
        const float* Wr0 = Wq + (d0 + 0) * 128;
        const float* Wr1 = Wq + (d0 + 1) * 128;
        const float* Wr2 = Wq + (d0 + 2) * 128;
        const float* Wr3 = Wq + (d0 + 3) * 128;
        for (int c = 0; c < 128; ++c) {
            float w0 = Wr0[c], w1 = Wr1[c], w2 = Wr2[c], w3 = Wr3[c];
            float4 xa = *(const float4*)&xs[c * XSS + i0];
            float4 xb = *(const float4*)&xs[c * XSS + i0 + 4];
            float xv[8] = {xa.x, xa.y, xa.z, xa.w, xb.x, xb.y, xb.z, xb.w};
            #pragma unroll
            for (int ii = 0; ii < 8; ++ii) {
                acc[0][ii] += w0 * xv[ii];
                acc[1][ii] += w1 * xv[ii];
                acc[2][ii] += w2 * xv[ii];
                acc[3][ii] += w3 * xv[ii];
            }
        }
        #pragma unroll
        for (int j = 0; j < 4; ++j)
            #pragma unroll
            for (int ii = 0; ii < 8; ++ii)
                qs[(d0 + j) * XSS + i0 + ii] = acc[j][ii];
    }
    __syncthreads();

    float o[4][8];   // PV accumulators: 4 i x 8 c
    #pragma unroll
    for (int a = 0; a < 4; ++a)
        #pragma unroll
        for (int cc = 0; cc < 8; ++cc) o[a][cc] = 0.f;
    float dsum_reg = 0.f;  // owned by threads 0..63 (t = i)

    for (int ch = 0; ch < 64; ++ch) {
        const int m0c = ch * 64;

        // (1) load raw x2 tile + p2 chunk
        #pragma unroll
        for (int u = 0; u < 32; ++u) {
            int idx = u * 256 + t;
            int mm = idx & 63, c = idx >> 6;
            xs[c * XSS + mm] = x2[((size_t)b * C_ + c) * M_ + m0c + mm];
        }
        if (t < 192) {
            int k3 = t >> 6, mm = t & 63;
            pp[k3 * 64 + mm] = p2[((size_t)b * 3 + k3) * M_ + m0c + mm];
        }
        __syncthreads();

        // (2) k[d][mm] = Wk.x2 + wkp.p2  -> kv
        {
            const int d0 = (t >> 3) * 4;
            const int mm0 = (t & 7) * 8;
            float acc[4][8];
            #pragma unroll
            for (int j = 0; j < 4; ++j)
                #pragma unroll
                for (int ii = 0; ii < 8; ++ii)
                    acc[j][ii] = wkp[(d0 + j) * 4 + 0] * pp[mm0 + ii]
                               + wkp[(d0 + j) * 4 + 1] * pp[64 + mm0 + ii]
                               + wkp[(d0 + j) * 4 + 2] * pp[128 + mm0 + ii];
            const float* Wr0 = Wk + (d0 + 0) * 128;
            const float* Wr1 = Wk + (d0 + 1) * 128;
            const float* Wr2 = Wk + (d0 + 2) * 128;
            const float* Wr3 = Wk + (d0 + 3) * 128;
            for (int c = 0; c < 128; ++c) {
                float w0 = Wr0[c], w1 = Wr1[c], w2 = Wr2[c], w3 = Wr3[c];
                float4 xa = *(const float4*)&xs[c * XSS + mm0];
                float4 xb = *(const float4*)&xs[c * XSS + mm0 + 4];
                float xv[8] = {xa.x, xa.y, xa.z, xa.w, xb.x, xb.y, xb.z, xb.w};
                #pragma unroll
                for (int ii = 0; ii < 8; ++ii) {
                    acc[0][ii] += w0 * xv[ii];
                    acc[1][ii] += w1 * xv[ii];
                    acc[2][ii] += w2 * xv[ii];
                    acc[3][ii] += w3 * xv[ii];
                }
            }
            #pragma unroll
            for (int j = 0; j < 4; ++j)
                #pragma unroll
                for (int ii = 0; ii < 8; ++ii)
                    kv[(d0 + j) * XSS + mm0 + ii] = acc[j][ii];
        }
        __syncthreads();

        // (3) S = q.k ; p = exp2(S*KS2) -> ps
        {
            const int i0 = (t & 15) * 4;
            const int mm0s = (t >> 4) * 4;
            float s[4][4];
            #pragma unroll
            for (int a = 0; a < 4; ++a)
                #pragma unroll
                for (int bb = 0; bb < 4; ++bb) s[a][bb] = 0.f;
            for (int d = 0; d < 128; ++d) {
                float4 qv = *(const float4*)&qs[d * XSS + i0];
                float4 kk = *(const float4*)&kv[d * XSS + mm0s];
                float qa[4] = {qv.x, qv.y, qv.z, qv.w};
                float ka[4] = {kk.x, kk.y, kk.z, kk.w};
                #pragma unroll
                for (int a = 0; a < 4; ++a)
                    #pragma unroll
                    for (int bb = 0; bb < 4; ++bb)
                        s[a][bb] += qa[a] * ka[bb];
            }
            #pragma unroll
            for (int a = 0; a < 4; ++a)
                #pragma unroll
                for (int bb = 0; bb < 4; ++bb) {
                    float e = fminf(s[a][bb] * KS2, 60.f);
                    ps[(i0 + a) * PSS + mm0s + bb] = __builtin_amdgcn_exp2f(e);
                }
        }
        __syncthreads();

        // (3b) denominators: thread i (<64) sums its ps row for this chunk
        if (t < 64) {
            float dacc = 0.f;
            #pragma unroll
            for (int mm4 = 0; mm4 < 16; ++mm4) {
                float4 pv = *(const float4*)&ps[t * PSS + mm4 * 4];
                dacc += pv.x + pv.y + pv.z + pv.w;
            }
            dsum_reg += dacc;
        }

        // (4) v[d][mm] = Wv.x2 -> kv (overwrites k; S done, barrier (3) passed)
        {
            const int d0 = (t >> 3) * 4;
            const int mm0 = (t & 7) * 8;
            float acc[4][8];
            #pragma unroll
            for (int j = 0; j < 4; ++j)
                #pragma unroll
                for (int ii = 0; ii < 8; ++ii) acc[j][ii] = 0.f;
            const float* Wr0 = Wv + (d0 + 0) * 128;
            const float* Wr1 = Wv + (d0 + 1) * 128;
            const float* Wr2 = Wv + (d0 + 2) * 128;
            const float* Wr3 = Wv + (d0 + 3) * 128;
            for (int c = 0; c < 128; ++c) {
                float w0 = Wr0[c], w1 = Wr1[c], w2 = Wr2[c], w3 = Wr3[c];
                float4 xa = *(const float4*)&xs[c * XSS + mm0];
                float4 xb = *(const float4*)&xs[c * XSS + mm0 + 4];
                float xv[8] = {xa.x, xa.y, xa.z, xa.w, xb.x, xb.y, xb.z, xb.w};
                #pragma unroll
                for (int ii = 0; ii < 8; ++ii) {
                    acc[0][ii] += w0 * xv[ii];
                    acc[1][ii] += w1 * xv[ii];
                    acc[2][ii] += w2 * xv[ii];
                    acc[3][ii] += w3 * xv[ii];
                }
            }
            #pragma unroll
            for (int j = 0; j < 4; ++j)
                #pragma unroll
                for (int ii = 0; ii < 8; ++ii)
                    kv[(d0 + j) * XSS + mm0 + ii] = acc[j][ii];
        }
        __syncthreads();

        // (5) PV: o[i][c] += sum_mm p[i][mm] * v[c][mm]
        {
            const int i0p = (t & 15) * 4;
            const int c0 = (t >> 4) * 8;
            #pragma unroll
            for (int mm4 = 0; mm4 < 16; ++mm4) {
                float4 pv4[4];
                #pragma unroll
                for (int a = 0; a < 4; ++a)
                    pv4[a] = *(const float4*)&ps[(i0p + a) * PSS + mm4 * 4];
                #pragma unroll
                for (int cc = 0; cc < 8; ++cc) {
                    float4 vv4 = *(const float4*)&kv[(c0 + cc) * XSS + mm4 * 4];
                    #pragma unroll
                    for (int a = 0; a < 4; ++a) {
                        o[a][cc] += pv4[a].x * vv4.x + pv4[a].y * vv4.y
                                  + pv4[a].z * vv4.z + pv4[a].w * vv4.w;
                    }
                }
            }
        }
        __syncthreads();   // protects xs/kv/ps for next chunk
    }

    // ---- epilogue: normalize, add residual, store FP32 [B,N,C] ----
    if (t < 64) dsums[t] = dsum_reg;
    __syncthreads();
    {
        const int i0p = (t & 15) * 4;
        const int c0 = (t >> 4) * 8;
        #pragma unroll
        for (int a = 0; a < 4; ++a) {
            int i = i0p + a, n = n0 + i;
            float linv = 1.0f / dsums[i];
            float4 lo, hi;
            float* vlo = &lo.x; float* vhi = &hi.x;
            #pragma unroll
            for (int cc = 0; cc < 4; ++cc) {
                vlo[cc] = o[a][cc] * linv + x1[((size_t)b * C_ + c0 + cc) * N_ + n];
                vhi[cc] = o[a][cc + 4] * linv + x1[((size_t)b * C_ + c0 + cc + 4) * N_ + n];
            }
            float* orow = out + ((size_t)b * N_ + n) * C_ + c0;
            *(float4*)(orow)     = lo;
            *(float4*)(orow + 4) = hi;
        }
    }
}

// ---------------------------------------------------------------------------
extern "C" void kernel_launch(void* const* d_in, const int* in_sizes, int n_in,
                              void* d_out, int out_size, void* d_ws, size_t ws_size,
                              hipStream_t stream) {
    const float* x1   = (const float*)d_in[0];
    const float* p1   = (const float*)d_in[1];
    const float* x2   = (const float*)d_in[2];
    const float* p2   = (const float*)d_in[3];
    const float* Wq   = (const float*)d_in[4];
    const float* Wk   = (const float*)d_in[5];
    const float* Wv   = (const float*)d_in[6];
    const float* Wpos = (const float*)d_in[7];
    float* out = (float*)d_out;

    fused_kernel<<<dim3(N_ / 64, B_), dim3(256), 0, stream>>>(
        x1, p1, x2, p2, Wq, Wk, Wv, Wpos, out);
}

// Round 12
// 359.510 us; speedup vs baseline: 5.2353x; 5.2353x over previous
//
#include <hip/hip_runtime.h>
#include <hip/hip_bf16.h>

#define B_ 4
#define C_ 128
#define N_ 4096
#define M_ 4096
#define XSS 68
#define PSS 68

typedef __bf16 bf16;
typedef __bf16 bf16x8 __attribute__((ext_vector_type(8)));
typedef float f32x4 __attribute__((ext_vector_type(4)));

#define MFMA16(a, b, c) __builtin_amdgcn_mfma_f32_16x16x32_bf16(a, b, c, 0, 0, 0)

__device__ inline bf16x8 cvt8(const float* p8) {
    float4 a = *(const float4*)p8;
    float4 b = *(const float4*)(p8 + 4);
    bf16x8 r;
    r[0] = (bf16)a.x; r[1] = (bf16)a.y; r[2] = (bf16)a.z; r[3] = (bf16)a.w;
    r[4] = (bf16)b.x; r[5] = (bf16)b.y; r[6] = (bf16)b.z; r[7] = (bf16)b.w;
    return r;
}

// ===========================================================================
// FAST PATH kernel 1: projections (fp32 in -> bf16 ws), pos folded at
// fragment build: q = Wq(x1 + Wpos p1), k = Wk(x2 + Wpos p2), v = Wv x2.
//  path 0: Qt[b][n][d];  path 1: Kt[b][m][d] and Vt[b][d][m]
// MFMA: A = W row (A[m=lane&15][k=quad*8+j]), B = x (B[k=c][n=lane&15]).
// D: row(d_local)=quad*4+reg, col(point)=lane&15.
// ===========================================================================
__global__ __launch_bounds__(256) void proj_kernel(
    const float* __restrict__ x1, const float* __restrict__ p1,
    const float* __restrict__ x2, const float* __restrict__ p2,
    const float* __restrict__ Wq, const float* __restrict__ Wk,
    const float* __restrict__ Wv, const float* __restrict__ Wpos,
    bf16* __restrict__ Qt, bf16* __restrict__ Kt, bf16* __restrict__ Vt) {
    const int path = blockIdx.z;
    const int b = blockIdx.y;
    const int w = threadIdx.x >> 6;
    const int lane = threadIdx.x & 63;
    const int col = lane & 15, quad = lane >> 4;
    const int n = blockIdx.x * 64 + w * 16 + col;

    const float* x = path ? x2 : x1;
    const float* p = path ? p2 : p1;
    const float* Wm = path ? Wk : Wq;
    bf16* Ot = path ? Kt : Qt;

    const float pv0 = p[(size_t)(b * 3 + 0) * N_ + n];
    const float pv1 = p[(size_t)(b * 3 + 1) * N_ + n];
    const float pv2 = p[(size_t)(b * 3 + 2) * N_ + n];

    bf16x8 bxp[4], bxr[4];
    #pragma unroll
    for (int cs = 0; cs < 4; ++cs)
        #pragma unroll
        for (int j = 0; j < 8; ++j) {
            int c = cs * 32 + quad * 8 + j;
            float xv = x[((size_t)b * C_ + c) * N_ + n];
            float pos = Wpos[c * 3 + 0] * pv0 + Wpos[c * 3 + 1] * pv1 +
                        Wpos[c * 3 + 2] * pv2;
            bxp[cs][j] = (bf16)(xv + pos);
            bxr[cs][j] = (bf16)xv;
        }

    #pragma unroll
    for (int dt = 0; dt < 8; ++dt) {
        f32x4 acc = {0.f, 0.f, 0.f, 0.f};
        #pragma unroll
        for (int cs = 0; cs < 4; ++cs) {
            bf16x8 wf = cvt8(Wm + (dt * 16 + col) * 128 + cs * 32 + quad * 8);
            acc = MFMA16(wf, bxp[cs], acc);
        }
        union { ushort4 u4; bf16 h[4]; } pk;
        #pragma unroll
        for (int r = 0; r < 4; ++r) pk.h[r] = (bf16)acc[r];
        *(ushort4*)(Ot + ((size_t)b * N_ + n) * C_ + dt * 16 + quad * 4) = pk.u4;
    }

    if (path) {
        #pragma unroll
        for (int dt = 0; dt < 8; ++dt) {
            f32x4 acc = {0.f, 0.f, 0.f, 0.f};
            #pragma unroll
            for (int cs = 0; cs < 4; ++cs) {
                bf16x8 wf = cvt8(Wv + (dt * 16 + col) * 128 + cs * 32 + quad * 8);
                acc = MFMA16(wf, bxr[cs], acc);
            }
            #pragma unroll
            for (int r = 0; r < 4; ++r)
                Vt[((size_t)b * C_ + dt * 16 + quad * 4 + r) * (size_t)M_ + n] = (bf16)acc[r];
        }
    }
}

// ===========================================================================
// FAST PATH kernel 2: flash attention + residual. fp32 x1 residual, fp32 out
// [B,N,C]. Grid (N/64, B); block 512 = 8 waves. Wave w: band=w&3 (16
// queries), half=w>>2 (2048-key half). No online max (|logit*scale| < ~6).
// P: MFMA C-layout -> wave-private LDS (stride 72) -> A-layout; explicit
// lgkmcnt(0) fence covers the cross-lane round-trip.
// ===========================================================================
__global__ __launch_bounds__(512) void attn_kernel(
    const bf16* __restrict__ Qt, const bf16* __restrict__ Kt,
    const bf16* __restrict__ Vt, const float* __restrict__ x1,
    float* __restrict__ out) {
    __shared__ __align__(16) bf16 pbuf[8][16 * 72];
    __shared__ float obuf[4][16 * 132];
    __shared__ float lbuf[4][16];

    const int w = threadIdx.x >> 6;
    const int lane = threadIdx.x & 63;
    const int col = lane & 15, quad = lane >> 4;
    const int band = w & 3, half = w >> 2;
    const int b = blockIdx.y;
    const int n0 = blockIdx.x * 64;

    const float KS = 0.12752107168406815f;  // log2(e)/sqrt(128)

    bf16x8 qf[4];
    {
        const bf16* Qb = Qt + ((size_t)b * N_ + n0 + band * 16 + col) * C_;
        #pragma unroll
        for (int cs = 0; cs < 4; ++cs)
            qf[cs] = *(const bf16x8*)(Qb + cs * 32 + quad * 8);
    }

    f32x4 oacc[8];
    #pragma unroll
    for (int t = 0; t < 8; ++t) oacc[t] = (f32x4){0.f, 0.f, 0.f, 0.f};
    float lacc[4] = {0.f, 0.f, 0.f, 0.f};

    bf16* pb = pbuf[w];

    for (int it = 0; it < 32; ++it) {
        const int m0 = half * 2048 + it * 64;
        const bf16* Kb = Kt + ((size_t)b * M_ + m0) * C_;

        // S = Q K^T: D[query][key], 4 key-subtiles x 4 c-steps
        f32x4 sacc[4];
        #pragma unroll
        for (int ms = 0; ms < 4; ++ms) sacc[ms] = (f32x4){0.f, 0.f, 0.f, 0.f};
        #pragma unroll
        for (int cs = 0; cs < 4; ++cs) {
            const int co = cs * 32 + quad * 8;
            #pragma unroll
            for (int ms = 0; ms < 4; ++ms) {
                bf16x8 kf = *(const bf16x8*)(Kb + (ms * 16 + col) * C_ + co);
                sacc[ms] = MFMA16(qf[cs], kf, sacc[ms]);
            }
        }

        // P = exp2(S*KS); per-lane row sums; stash P[query][key] in LDS
        #pragma unroll
        for (int ms = 0; ms < 4; ++ms)
            #pragma unroll
            for (int r = 0; r < 4; ++r) {
                float e = fminf(sacc[ms][r] * KS, 60.f);
                float pvv = __builtin_amdgcn_exp2f(e);
                lacc[r] += pvv;
                pb[(quad * 4 + r) * 72 + ms * 16 + col] = (bf16)pvv;
            }

        // cross-lane LDS round-trip fence (write above, transposed read below)
        asm volatile("s_waitcnt lgkmcnt(0)" ::: "memory");

        // O += P V^T: A = P (A[m=query=lane&15][k=key=quad*8+j]), B = V[c][m]
        const bf16* Vb = Vt + (size_t)b * C_ * M_ + m0;
        #pragma unroll
        for (int ks = 0; ks < 2; ++ks) {
            bf16x8 af = *(const bf16x8*)(pb + col * 72 + ks * 32 + quad * 8);
            #pragma unroll
            for (int t = 0; t < 8; ++t) {
                bf16x8 vf = *(const bf16x8*)(Vb + (size_t)(t * 16 + col) * M_ + ks * 32 + quad * 8);
                oacc[t] = MFMA16(af, vf, oacc[t]);
            }
        }
    }

    // reduce row sums across the 16 key-columns (lane bits 0-3)
    #pragma unroll
    for (int r = 0; r < 4; ++r)
        #pragma unroll
        for (int off = 1; off < 16; off <<= 1)
            lacc[r] += __shfl_xor(lacc[r], off, 64);

    if (half == 1) {
        #pragma unroll
        for (int t = 0; t < 8; ++t)
            #pragma unroll
            for (int r = 0; r < 4; ++r)
                obuf[band][(quad * 4 + r) * 132 + t * 16 + col] = oacc[t][r];
        if (col == 0)
            #pragma unroll
            for (int r = 0; r < 4; ++r)
                lbuf[band][quad * 4 + r] = lacc[r];
    }
    __syncthreads();
    if (half == 0) {
        float linv[4];
        #pragma unroll
        for (int r = 0; r < 4; ++r)
            linv[r] = 1.0f / (lacc[r] + lbuf[band][quad * 4 + r]);
        #pragma unroll
        for (int t = 0; t < 8; ++t) {
            #pragma unroll
            for (int r = 0; r < 4; ++r) {
                int n = n0 + band * 16 + quad * 4 + r;
                int c = t * 16 + col;
                float o = (oacc[t][r] + obuf[band][(quad * 4 + r) * 132 + t * 16 + col]) * linv[r];
                float xr = x1[((size_t)b * C_ + c) * N_ + n];
                out[((size_t)b * N_ + n) * C_ + c] = o + xr;
            }
        }
    }
}

// ===========================================================================
// FALLBACK: round-11's proven fp32 vector kernel (used iff ws too small).
// ===========================================================================
__global__ __launch_bounds__(256) void fused_kernel(
    const float* __restrict__ x1, const float* __restrict__ p1,
    const float* __restrict__ x2, const float* __restrict__ p2,
    const float* __restrict__ Wq, const float* __restrict__ Wk,
    const float* __restrict__ Wv, const float* __restrict__ Wpos,
    float* __restrict__ out) {

    __shared__ float xs[128 * XSS];
    __shared__ float qs[128 * XSS];
    __shared__ float kv[128 * XSS];
    __shared__ float ps[64 * PSS];
    __shared__ float wqp[128 * 4];
    __shared__ float wkp[128 * 4];
    __shared__ float pp[3 * 64];
    __shared__ float dsums[64];

    const int t = threadIdx.x;
    const int b = blockIdx.y;
    const int n0 = blockIdx.x * 64;
    const float KS2 = 0.12752107168406815f;

    for (int idx = t; idx < 768; idx += 256) {
        int which = idx / 384;
        int rem = idx - which * 384;
        int d = rem / 3;
        int k3 = rem - d * 3;
        const float* W = which ? Wk : Wq;
        float s = 0.f;
        #pragma unroll 8
        for (int c = 0; c < 128; ++c)
            s += W[d * 128 + c] * Wpos[c * 3 + k3];
        (which ? wkp : wqp)[d * 4 + k3] = s;
    }

    #pragma unroll
    for (int u = 0; u < 32; ++u) {
        int idx = u * 256 + t;
        int i = idx & 63, c = idx >> 6;
        xs[c * XSS + i] = x1[((size_t)b * C_ + c) * N_ + n0 + i];
    }
    if (t < 192) {
        int k3 = t >> 6, i = t & 63;
        pp[k3 * 64 + i] = p1[((size_t)b * 3 + k3) * N_ + n0 + i];
    }
    __syncthreads();

    {
        const int d0 = (t >> 3) * 4;
        const int i0 = (t & 7) * 8;
        float acc[4][8];
        #pragma unroll
        for (int j = 0; j < 4; ++j)
            #pragma unroll
            for (int ii = 0; ii < 8; ++ii)
                acc[j][ii] = wqp[(d0 + j) * 4 + 0] * pp[i0 + ii]
                           + wqp[(d0 + j) * 4 + 1] * pp[64 + i0 + ii]
                           + wqp[(d0 + j) * 4 + 2] * pp[128 + i0 + ii];
        const float* Wr0 = Wq + (d0 + 0) * 128;
        const float* Wr1 = Wq + (d0 + 1) * 128;
        const float* Wr2 = Wq + (d0 + 2) * 128;
        const float* Wr3 = Wq + (d0 + 3) * 128;
        for (int c = 0; c < 128; ++c) {
            float w0 = Wr0[c], w1 = Wr1[c], w2 = Wr2[c], w3 = Wr3[c];
            float4 xa = *(const float4*)&xs[c * XSS + i0];
            float4 xb = *(const float4*)&xs[c * XSS + i0 + 4];
            float xv[8] = {xa.x, xa.y, xa.z, xa.w, xb.x, xb.y, xb.z, xb.w};
            #pragma unroll
            for (int ii = 0; ii < 8; ++ii) {
                acc[0][ii] += w0 * xv[ii];
                acc[1][ii] += w1 * xv[ii];
                acc[2][ii] += w2 * xv[ii];
                acc[3][ii] += w3 * xv[ii];
            }
        }
        #pragma unroll
        for (int j = 0; j < 4; ++j)
            #pragma unroll
            for (int ii = 0; ii < 8; ++ii)
                qs[(d0 + j) * XSS + i0 + ii] = acc[j][ii];
    }
    __syncthreads();

    float o[4][8];
    #pragma unroll
    for (int a = 0; a < 4; ++a)
        #pragma unroll
        for (int cc = 0; cc < 8; ++cc) o[a][cc] = 0.f;
    float dsum_reg = 0.f;

    for (int ch = 0; ch < 64; ++ch) {
        const int m0c = ch * 64;
        #pragma unroll
        for (int u = 0; u < 32; ++u) {
            int idx = u * 256 + t;
            int mm = idx & 63, c = idx >> 6;
            xs[c * XSS + mm] = x2[((size_t)b * C_ + c) * M_ + m0c + mm];
        }
        if (t < 192) {
            int k3 = t >> 6, mm = t & 63;
            pp[k3 * 64 + mm] = p2[((size_t)b * 3 + k3) * M_ + m0c + mm];
        }
        __syncthreads();

        {
            const int d0 = (t >> 3) * 4;
            const int mm0 = (t & 7) * 8;
            float acc[4][8];
            #pragma unroll
            for (int j = 0; j < 4; ++j)
                #pragma unroll
                for (int ii = 0; ii < 8; ++ii)
                    acc[j][ii] = wkp[(d0 + j) * 4 + 0] * pp[mm0 + ii]
                               + wkp[(d0 + j) * 4 + 1] * pp[64 + mm0 + ii]
                               + wkp[(d0 + j) * 4 + 2] * pp[128 + mm0 + ii];
            const float* Wr0 = Wk + (d0 + 0) * 128;
            const float* Wr1 = Wk + (d0 + 1) * 128;
            const float* Wr2 = Wk + (d0 + 2) * 128;
            const float* Wr3 = Wk + (d0 + 3) * 128;
            for (int c = 0; c < 128; ++c) {
                float w0 = Wr0[c], w1 = Wr1[c], w2 = Wr2[c], w3 = Wr3[c];
                float4 xa = *(const float4*)&xs[c * XSS + mm0];
                float4 xb = *(const float4*)&xs[c * XSS + mm0 + 4];
                float xv[8] = {xa.x, xa.y, xa.z, xa.w, xb.x, xb.y, xb.z, xb.w};
                #pragma unroll
                for (int ii = 0; ii < 8; ++ii) {
                    acc[0][ii] += w0 * xv[ii];
                    acc[1][ii] += w1 * xv[ii];
                    acc[2][ii] += w2 * xv[ii];
                    acc[3][ii] += w3 * xv[ii];
                }
            }
            #pragma unroll
            for (int j = 0; j < 4; ++j)
                #pragma unroll
                for (int ii = 0; ii < 8; ++ii)
                    kv[(d0 + j) * XSS + mm0 + ii] = acc[j][ii];
        }
        __syncthreads();

        {
            const int i0 = (t & 15) * 4;
            const int mm0s = (t >> 4) * 4;
            float s[4][4];
            #pragma unroll
            for (int a = 0; a < 4; ++a)
                #pragma unroll
                for (int bb = 0; bb < 4; ++bb) s[a][bb] = 0.f;
            for (int d = 0; d < 128; ++d) {
                float4 qv = *(const float4*)&qs[d * XSS + i0];
                float4 kk = *(const float4*)&kv[d * XSS + mm0s];
                float qa[4] = {qv.x, qv.y, qv.z, qv.w};
                float ka[4] = {kk.x, kk.y, kk.z, kk.w};
                #pragma unroll
                for (int a = 0; a < 4; ++a)
                    #pragma unroll
                    for (int bb = 0; bb < 4; ++bb)
                        s[a][bb] += qa[a] * ka[bb];
            }
            #pragma unroll
            for (int a = 0; a < 4; ++a)
                #pragma unroll
                for (int bb = 0; bb < 4; ++bb) {
                    float e = fminf(s[a][bb] * KS2, 60.f);
                    ps[(i0 + a) * PSS + mm0s + bb] = __builtin_amdgcn_exp2f(e);
                }
        }
        __syncthreads();

        if (t < 64) {
            float dacc = 0.f;
            #pragma unroll
            for (int mm4 = 0; mm4 < 16; ++mm4) {
                float4 pv = *(const float4*)&ps[t * PSS + mm4 * 4];
                dacc += pv.x + pv.y + pv.z + pv.w;
            }
            dsum_reg += dacc;
        }

        {
            const int d0 = (t >> 3) * 4;
            const int mm0 = (t & 7) * 8;
            float acc[4][8];
            #pragma unroll
            for (int j = 0; j < 4; ++j)
                #pragma unroll
                for (int ii = 0; ii < 8; ++ii) acc[j][ii] = 0.f;
            const float* Wr0 = Wv + (d0 + 0) * 128;
            const float* Wr1 = Wv + (d0 + 1) * 128;
            const float* Wr2 = Wv + (d0 + 2) * 128;
            const float* Wr3 = Wv + (d0 + 3) * 128;
            for (int c = 0; c < 128; ++c) {
                float w0 = Wr0[c], w1 = Wr1[c], w2 = Wr2[c], w3 = Wr3[c];
                float4 xa = *(const float4*)&xs[c * XSS + mm0];
                float4 xb = *(const float4*)&xs[c * XSS + mm0 + 4];
                float xv[8] = {xa.x, xa.y, xa.z, xa.w, xb.x, xb.y, xb.z, xb.w};
                #pragma unroll
                for (int ii = 0; ii < 8; ++ii) {
                    acc[0][ii] += w0 * xv[ii];
                    acc[1][ii] += w1 * xv[ii];
                    acc[2][ii] += w2 * xv[ii];
                    acc[3][ii] += w3 * xv[ii];
                }
            }
            #pragma unroll
            for (int j = 0; j < 4; ++j)
                #pragma unroll
                for (int ii = 0; ii < 8; ++ii)
                    kv[(d0 + j) * XSS + mm0 + ii] = acc[j][ii];
        }
        __syncthreads();

        {
            const int i0p = (t & 15) * 4;
            const int c0 = (t >> 4) * 8;
            #pragma unroll
            for (int mm4 = 0; mm4 < 16; ++mm4) {
                float4 pv4[4];
                #pragma unroll
                for (int a = 0; a < 4; ++a)
                    pv4[a] = *(const float4*)&ps[(i0p + a) * PSS + mm4 * 4];
                #pragma unroll
                for (int cc = 0; cc < 8; ++cc) {
                    float4 vv4 = *(const float4*)&kv[(c0 + cc) * XSS + mm4 * 4];
                    #pragma unroll
                    for (int a = 0; a < 4; ++a) {
                        o[a][cc] += pv4[a].x * vv4.x + pv4[a].y * vv4.y
                                  + pv4[a].z * vv4.z + pv4[a].w * vv4.w;
                    }
                }
            }
        }
        __syncthreads();
    }

    if (t < 64) dsums[t] = dsum_reg;
    __syncthreads();
    {
        const int i0p = (t & 15) * 4;
        const int c0 = (t >> 4) * 8;
        #pragma unroll
        for (int a = 0; a < 4; ++a) {
            int i = i0p + a, n = n0 + i;
            float linv = 1.0f / dsums[i];
            float4 lo, hi;
            float* vlo = &lo.x; float* vhi = &hi.x;
            #pragma unroll
            for (int cc = 0; cc < 4; ++cc) {
                vlo[cc] = o[a][cc] * linv + x1[((size_t)b * C_ + c0 + cc) * N_ + n];
                vhi[cc] = o[a][cc + 4] * linv + x1[((size_t)b * C_ + c0 + cc + 4) * N_ + n];
            }
            float* orow = out + ((size_t)b * N_ + n) * C_ + c0;
            *(float4*)(orow)     = lo;
            *(float4*)(orow + 4) = hi;
        }
    }
}

// ---------------------------------------------------------------------------
extern "C" void kernel_launch(void* const* d_in, const int* in_sizes, int n_in,
                              void* d_out, int out_size, void* d_ws, size_t ws_size,
                              hipStream_t stream) {
    const float* x1   = (const float*)d_in[0];
    const float* p1   = (const float*)d_in[1];
    const float* x2   = (const float*)d_in[2];
    const float* p2   = (const float*)d_in[3];
    const float* Wq   = (const float*)d_in[4];
    const float* Wk   = (const float*)d_in[5];
    const float* Wv   = (const float*)d_in[6];
    const float* Wpos = (const float*)d_in[7];
    float* out = (float*)d_out;

    const size_t need = (size_t)3 * B_ * N_ * C_ * sizeof(bf16);  // 12.58 MB
    if (ws_size >= need) {
        bf16* Qt = (bf16*)d_ws;                                  // [B][N][C]
        bf16* Kt = Qt + (size_t)B_ * N_ * C_;                    // [B][M][C]
        bf16* Vt = Kt + (size_t)B_ * M_ * C_;                    // [B][C][M]
        proj_kernel<<<dim3(64, B_, 2), dim3(256), 0, stream>>>(
            x1, p1, x2, p2, Wq, Wk, Wv, Wpos, Qt, Kt, Vt);
        attn_kernel<<<dim3(64, B_), dim3(512), 0, stream>>>(Qt, Kt, Vt, x1, out);
    } else {
        fused_kernel<<<dim3(N_ / 64, B_), dim3(256), 0, stream>>>(
            x1, p1, x2, p2, Wq, Wk, Wv, Wpos, out);
    }
}

// Round 13
// 330.628 us; speedup vs baseline: 5.6926x; 1.0874x over previous
//
#include <hip/hip_runtime.h>
#include <hip/hip_bf16.h>

#define B_ 4
#define C_ 128
#define N_ 4096
#define M_ 4096

typedef __bf16 bf16;
typedef __bf16 bf16x8 __attribute__((ext_vector_type(8)));
typedef float f32x4 __attribute__((ext_vector_type(4)));

#define MFMA16(a, b, c) __builtin_amdgcn_mfma_f32_16x16x32_bf16(a, b, c, 0, 0, 0)

__device__ inline bf16x8 cvt8(const float* p8) {
    float4 a = *(const float4*)p8;
    float4 b = *(const float4*)(p8 + 4);
    bf16x8 r;
    r[0] = (bf16)a.x; r[1] = (bf16)a.y; r[2] = (bf16)a.z; r[3] = (bf16)a.w;
    r[4] = (bf16)b.x; r[5] = (bf16)b.y; r[6] = (bf16)b.z; r[7] = (bf16)b.w;
    return r;
}

// ===========================================================================
// Kernel 1: projections (fp32 in -> bf16 ws), pos folded at fragment build.
// grid.z: 0 = Q (x1,p1,Wq -> Qt[b][n][c]), 1 = K (x2,p2,Wk -> Kt[b][m][c]),
//         2 = V (x2,Wv -> Vt[b][c][m], no pos).
// 768 blocks -> 3 blocks/CU -> 12 waves/CU (R12 proj was 2 blocks/CU and
// latency-bound on stride-16KB x gathers).
// MFMA: A = W row (A[m=lane&15][k=quad*8+j]), B = x (B[k=c][n=lane&15]).
// D: row(d_local)=quad*4+reg, col(point)=lane&15.
// ===========================================================================
__global__ __launch_bounds__(256) void proj_kernel(
    const float* __restrict__ x1, const float* __restrict__ p1,
    const float* __restrict__ x2, const float* __restrict__ p2,
    const float* __restrict__ Wq, const float* __restrict__ Wk,
    const float* __restrict__ Wv, const float* __restrict__ Wpos,
    bf16* __restrict__ Qt, bf16* __restrict__ Kt, bf16* __restrict__ Vt) {
    const int path = blockIdx.z;
    const int b = blockIdx.y;
    const int w = threadIdx.x >> 6;
    const int lane = threadIdx.x & 63;
    const int col = lane & 15, quad = lane >> 4;
    const int n = blockIdx.x * 64 + w * 16 + col;

    const float* x = (path == 0) ? x1 : x2;
    const float* Wm = (path == 0) ? Wq : (path == 1) ? Wk : Wv;

    bf16x8 bx[4];
    if (path < 2) {
        const float* p = (path == 0) ? p1 : p2;
        const float pv0 = p[(size_t)(b * 3 + 0) * N_ + n];
        const float pv1 = p[(size_t)(b * 3 + 1) * N_ + n];
        const float pv2 = p[(size_t)(b * 3 + 2) * N_ + n];
        #pragma unroll
        for (int cs = 0; cs < 4; ++cs)
            #pragma unroll
            for (int j = 0; j < 8; ++j) {
                int c = cs * 32 + quad * 8 + j;
                float xv = x[((size_t)b * C_ + c) * N_ + n];
                float pos = Wpos[c * 3 + 0] * pv0 + Wpos[c * 3 + 1] * pv1 +
                            Wpos[c * 3 + 2] * pv2;
                bx[cs][j] = (bf16)(xv + pos);
            }
    } else {
        #pragma unroll
        for (int cs = 0; cs < 4; ++cs)
            #pragma unroll
            for (int j = 0; j < 8; ++j) {
                int c = cs * 32 + quad * 8 + j;
                bx[cs][j] = (bf16)x[((size_t)b * C_ + c) * N_ + n];
            }
    }

    #pragma unroll
    for (int dt = 0; dt < 8; ++dt) {
        f32x4 acc = {0.f, 0.f, 0.f, 0.f};
        #pragma unroll
        for (int cs = 0; cs < 4; ++cs) {
            bf16x8 wf = cvt8(Wm + (dt * 16 + col) * 128 + cs * 32 + quad * 8);
            acc = MFMA16(wf, bx[cs], acc);
        }
        if (path < 2) {
            bf16* Ot = (path == 0) ? Qt : Kt;
            union { ushort4 u4; bf16 h[4]; } pk;
            #pragma unroll
            for (int r = 0; r < 4; ++r) pk.h[r] = (bf16)acc[r];
            *(ushort4*)(Ot + ((size_t)b * N_ + n) * C_ + dt * 16 + quad * 4) = pk.u4;
        } else {
            #pragma unroll
            for (int r = 0; r < 4; ++r)
                Vt[((size_t)b * C_ + dt * 16 + quad * 4 + r) * (size_t)M_ + n] = (bf16)acc[r];
        }
    }
}

// ===========================================================================
// Kernel 2: flash attention + residual. fp32 x1 residual, fp32 out [B,N,C].
// Grid (N/32, B) = 512 blocks; block 512 = 8 waves: band = w&1 (16 queries),
// quarter = w>>1 (1024 keys, 16 iters of 64). 2 blocks/CU -> 16 waves/CU
// (R12 was 8 waves/CU, MfmaUtil 5%, latency-bound).
// No online max (|logit*scale| < ~6, clamped). P: MFMA C-layout ->
// wave-private LDS (stride 72) -> A-layout, lgkmcnt(0) fence.
// End: 2-step LDS tree merge over the 4 quarters per band.
// ===========================================================================
__global__ __launch_bounds__(512) void attn_kernel(
    const bf16* __restrict__ Qt, const bf16* __restrict__ Kt,
    const bf16* __restrict__ Vt, const float* __restrict__ x1,
    float* __restrict__ out) {
    __shared__ __align__(16) bf16 pbuf[8][16 * 72];   // 18.4 KB
    __shared__ float obuf[4][16 * 132];               // 33.8 KB (merge slots)
    __shared__ float lbuf[4][16];

    const int w = threadIdx.x >> 6;
    const int lane = threadIdx.x & 63;
    const int col = lane & 15, quad = lane >> 4;
    const int band = w & 1, q = w >> 1;
    const int b = blockIdx.y;
    const int n0 = blockIdx.x * 32;

    const float KS = 0.12752107168406815f;  // log2(e)/sqrt(128)

    bf16x8 qf[4];
    {
        const bf16* Qb = Qt + ((size_t)b * N_ + n0 + band * 16 + col) * C_;
        #pragma unroll
        for (int cs = 0; cs < 4; ++cs)
            qf[cs] = *(const bf16x8*)(Qb + cs * 32 + quad * 8);
    }

    f32x4 oacc[8];
    #pragma unroll
    for (int t = 0; t < 8; ++t) oacc[t] = (f32x4){0.f, 0.f, 0.f, 0.f};
    float lacc[4] = {0.f, 0.f, 0.f, 0.f};

    bf16* pb = pbuf[w];

    for (int it = 0; it < 16; ++it) {
        const int m0 = q * 1024 + it * 64;
        const bf16* Kb = Kt + ((size_t)b * M_ + m0) * C_;

        // S = Q K^T: D[query][key], 4 key-subtiles x 4 c-steps
        f32x4 sacc[4];
        #pragma unroll
        for (int ms = 0; ms < 4; ++ms) sacc[ms] = (f32x4){0.f, 0.f, 0.f, 0.f};
        #pragma unroll
        for (int cs = 0; cs < 4; ++cs) {
            const int co = cs * 32 + quad * 8;
            #pragma unroll
            for (int ms = 0; ms < 4; ++ms) {
                bf16x8 kf = *(const bf16x8*)(Kb + (ms * 16 + col) * C_ + co);
                sacc[ms] = MFMA16(qf[cs], kf, sacc[ms]);
            }
        }

        // P = exp2(S*KS); per-lane row sums; stash P[query][key] in LDS
        #pragma unroll
        for (int ms = 0; ms < 4; ++ms)
            #pragma unroll
            for (int r = 0; r < 4; ++r) {
                float e = fminf(sacc[ms][r] * KS, 60.f);
                float pvv = __builtin_amdgcn_exp2f(e);
                lacc[r] += pvv;
                pb[(quad * 4 + r) * 72 + ms * 16 + col] = (bf16)pvv;
            }

        asm volatile("s_waitcnt lgkmcnt(0)" ::: "memory");

        // O += P V^T: A = P (A[m=query][k=key]), B = V[c][m]
        const bf16* Vb = Vt + (size_t)b * C_ * M_ + m0;
        #pragma unroll
        for (int ks = 0; ks < 2; ++ks) {
            bf16x8 af = *(const bf16x8*)(pb + col * 72 + ks * 32 + quad * 8);
            #pragma unroll
            for (int t = 0; t < 8; ++t) {
                bf16x8 vf = *(const bf16x8*)(Vb + (size_t)(t * 16 + col) * M_ + ks * 32 + quad * 8);
                oacc[t] = MFMA16(af, vf, oacc[t]);
            }
        }
    }

    // reduce row sums across the 16 key-columns (lane bits 0-3)
    #pragma unroll
    for (int r = 0; r < 4; ++r)
        #pragma unroll
        for (int off = 1; off < 16; off <<= 1)
            lacc[r] += __shfl_xor(lacc[r], off, 64);

    // ---- merge tree over quarters: (0+2), (1+3), then (01 + 23) ----
    if (q >= 2) {
        const int slot = band * 2 + (q - 2);
        #pragma unroll
        for (int t = 0; t < 8; ++t)
            #pragma unroll
            for (int r = 0; r < 4; ++r)
                obuf[slot][(quad * 4 + r) * 132 + t * 16 + col] = oacc[t][r];
        if (col == 0)
            #pragma unroll
            for (int r = 0; r < 4; ++r)
                lbuf[slot][quad * 4 + r] = lacc[r];
    }
    __syncthreads();
    if (q < 2) {
        const int slot = band * 2 + q;
        #pragma unroll
        for (int t = 0; t < 8; ++t)
            #pragma unroll
            for (int r = 0; r < 4; ++r)
                oacc[t][r] += obuf[slot][(quad * 4 + r) * 132 + t * 16 + col];
        #pragma unroll
        for (int r = 0; r < 4; ++r)
            lacc[r] += lbuf[slot][quad * 4 + r];
    }
    __syncthreads();
    if (q == 1) {
        const int slot = band * 2 + 1;
        #pragma unroll
        for (int t = 0; t < 8; ++t)
            #pragma unroll
            for (int r = 0; r < 4; ++r)
                obuf[slot][(quad * 4 + r) * 132 + t * 16 + col] = oacc[t][r];
        if (col == 0)
            #pragma unroll
            for (int r = 0; r < 4; ++r)
                lbuf[slot][quad * 4 + r] = lacc[r];
    }
    __syncthreads();
    if (q == 0) {
        const int slot = band * 2 + 1;
        float linv[4];
        #pragma unroll
        for (int r = 0; r < 4; ++r)
            linv[r] = 1.0f / (lacc[r] + lbuf[slot][quad * 4 + r]);
        #pragma unroll
        for (int t = 0; t < 8; ++t) {
            #pragma unroll
            for (int r = 0; r < 4; ++r) {
                int n = n0 + band * 16 + quad * 4 + r;
                int c = t * 16 + col;
                float o = (oacc[t][r] + obuf[slot][(quad * 4 + r) * 132 + t * 16 + col]) * linv[r];
                float xr = x1[((size_t)b * C_ + c) * N_ + n];
                out[((size_t)b * N_ + n) * C_ + c] = o + xr;
            }
        }
    }
}

// ---------------------------------------------------------------------------
extern "C" void kernel_launch(void* const* d_in, const int* in_sizes, int n_in,
                              void* d_out, int out_size, void* d_ws, size_t ws_size,
                              hipStream_t stream) {
    const float* x1   = (const float*)d_in[0];
    const float* p1   = (const float*)d_in[1];
    const float* x2   = (const float*)d_in[2];
    const float* p2   = (const float*)d_in[3];
    const float* Wq   = (const float*)d_in[4];
    const float* Wk   = (const float*)d_in[5];
    const float* Wv   = (const float*)d_in[6];
    const float* Wpos = (const float*)d_in[7];
    float* out = (float*)d_out;

    bf16* Qt = (bf16*)d_ws;                 // [B][N][C]  (ws >= 12.6 MB proven R12)
    bf16* Kt = Qt + (size_t)B_ * N_ * C_;   // [B][M][C]
    bf16* Vt = Kt + (size_t)B_ * M_ * C_;   // [B][C][M]

    proj_kernel<<<dim3(64, B_, 3), dim3(256), 0, stream>>>(
        x1, p1, x2, p2, Wq, Wk, Wv, Wpos, Qt, Kt, Vt);
    attn_kernel<<<dim3(N_ / 32, B_), dim3(512), 0, stream>>>(Qt, Kt, Vt, x1, out);
}